// Round 9
// baseline (61.259 us; speedup 1.0000x reference)
//
#include <hip/hip_runtime.h>
#include <stdint.h>
#include <stddef.h>

// Problem constants
#define D_FEAT 1280
#define N_PAD  256
#define N_OUT  248
#define BM     32
#define BK     64
#define K_ITERS 20
#define W_TILE_BYTES (N_PAD * BK * 2)   // 32 KB bf16 weight tile (all 256 cols)

typedef float f32x4 __attribute__((ext_vector_type(4)));
typedef short s16x8 __attribute__((ext_vector_type(8)));
typedef unsigned int u32x4 __attribute__((ext_vector_type(4)));

// one v_cvt_pk_bf16_f32: packs 2 fp32 -> 2 bf16 (RTNE), lo=a, hi=b
__device__ __forceinline__ unsigned int cvt_pk(float a, float b) {
  unsigned int r;
  asm("v_cvt_pk_bf16_f32 %0, %1, %2" : "=v"(r) : "v"(a), "v"(b));
  return r;
}

__device__ __forceinline__ void gload16(const void* g, void* l) {
  __builtin_amdgcn_global_load_lds(
      (const __attribute__((address_space(1))) void*)g,
      (__attribute__((address_space(3))) void*)l, 16, 0, 0);
}

// ---------------------------------------------------------------------------
// Pack W_final (D,8), Wp1 (8,D,6), Wp2 (8,6,D,4) into one bf16 matrix laid out
// exactly as the main kernel's LDS B-tiles expect (XOR swizzle pre-baked so
// global_load_lds is a LINEAR copy and ds_read_b128 is conflict-free).
// Tile kt: [n=0..255][s_phys=0..7] 16B chunks; chunk(n,s_phys) holds
// W[n][kt*64 + 8*(s_phys ^ (n&7)) .. +7].  One thread = one 16B chunk.
// n-major => cols 64w..64w+63 of a tile are one contiguous 8KB range (the
// per-wave quarter the main kernel stages).
// ---------------------------------------------------------------------------
__global__ __launch_bounds__(256) void pack_w_kernel(
    const float* __restrict__ Wf, const float* __restrict__ Wp1,
    const float* __restrict__ Wp2, unsigned short* __restrict__ out) {
  int chunk = blockIdx.x * 256 + threadIdx.x;    // 0 .. 40959
  int s_phys = chunk & 7;
  int n = (chunk >> 3) & 255;
  int kt = chunk >> 11;
  int s_log = s_phys ^ (n & 7);
  int d0 = kt * BK + s_log * 8;
  float v[8];
#pragma unroll
  for (int e = 0; e < 8; ++e) v[e] = 0.0f;
  if (n < 8) {
#pragma unroll
    for (int e = 0; e < 8; ++e) v[e] = Wf[(d0 + e) * 8 + n];
  } else if (n < 56) {
    int m = n - 8;
    const float* base = Wp1 + (size_t)(m / 6) * D_FEAT * 6 + (m % 6);
#pragma unroll
    for (int e = 0; e < 8; ++e) v[e] = base[(d0 + e) * 6];
  } else if (n < 248) {
    int m = n - 56;
    const float* base = Wp2 + ((size_t)(m / 24) * 6 + ((m % 24) >> 2)) * D_FEAT * 4 + (m & 3);
#pragma unroll
    for (int e = 0; e < 8; ++e) v[e] = base[(d0 + e) * 4];
  }
  union { u32x4 u; s16x8 s; } pk;
#pragma unroll
  for (int h = 0; h < 4; ++h) pk.u[h] = cvt_pk(v[2 * h], v[2 * h + 1]);
  *(s16x8*)(out + (size_t)chunk * 8) = pk.s;
}

// ---------------------------------------------------------------------------
// BARRIER-FREE fused GEMM (bf16 MFMA) + hierarchical softmax epilogue.
// 256 threads = 4 waves (1M x 4N), BM=32, grid 512, 2 blocks/CU (64KB LDS).
// Wave w consumes ONLY B cols [64w,64w+64) -> it stages its own 8KB quarter
// into its own LDS double-buffer and loads its A fragments global->reg.
// ZERO cross-wave data flow in the K-loop => NO s_barrier at all; each wave
// is a self-clocked pipeline ordered by its own vmcnt. Dbuf WAR hazards are
// resolved by single-wave program order (ds_reads of tile kt-1 complete
// before their MFMAs issue, which precede the kt+1 stage issue).
// Per iter: vmcnt(8) retires A(kt)+B(kt) (A(kt+1) stays in flight);
// issue B(kt+1)+A(kt+2); cvt A(kt); 16 MFMA wrapped in s_setprio (T5 —
// pays in the drifting-wave regime, m191). A: 3 reg slots = 2-iter flight.
// ---------------------------------------------------------------------------
__global__ __launch_bounds__(256, 2) void tree_head_kernel(
    const float* __restrict__ x, const unsigned short* __restrict__ Wb,
    const float* __restrict__ b_final, const float* __restrict__ wu1,
    const float* __restrict__ b1, const float* __restrict__ wu2,
    const float* __restrict__ b2, float* __restrict__ out) {
  __shared__ __align__(16) char smem[65536];   // 4 waves x (2 x 8KB B dbuf)

  const int tid  = threadIdx.x;
  const int lane = tid & 63;
  const int wave = tid >> 6;       // 0..3 = N quarter
  const int l15  = lane & 15;
  const int lh   = lane >> 4;      // 0..3
  const int row0 = blockIdx.x * BM;

  char* Bme = smem + wave * 16384;             // this wave's dbuf: +0 / +8192

  f32x4 acc[2][4];
#pragma unroll
  for (int m = 0; m < 2; ++m)
#pragma unroll
    for (int n = 0; n < 4; ++n)
#pragma unroll
      for (int j = 0; j < 4; ++j) acc[m][n][j] = 0.0f;

  // A: per-lane direct loads. Lane covers rows row0 + m*16 + l15 (m=0,1),
  // k-slice lh*8 within each 32-wide ks step. 8 x f32x4 per tile.
  const char* abase = (const char*)x
      + ((size_t)(row0 + l15) * D_FEAT + lh * 8) * 4;
  // B: this wave's contiguous 8KB quarter of the packed tile.
  const char* bsrc = (const char*)Wb + wave * 8192 + lane * 16;

  f32x4 ra[3][8];   // [slot][m*4 + ks*2 + h], 3-slot rotation (static idx)

#define STAGEB(kt_, db_) do {                                                 \
    _Pragma("unroll")                                                         \
    for (int j_ = 0; j_ < 8; ++j_)                                            \
      gload16(bsrc + (size_t)(kt_) * W_TILE_BYTES + j_ * 1024,                \
              Bme + (db_) * 8192 + j_ * 1024);                                \
  } while (0)

#define LOADA(kt_, s_) do {                                                   \
    _Pragma("unroll")                                                         \
    for (int m_ = 0; m_ < 2; ++m_)                                            \
      _Pragma("unroll")                                                       \
      for (int ks_ = 0; ks_ < 2; ++ks_)                                       \
        _Pragma("unroll")                                                     \
        for (int h_ = 0; h_ < 2; ++h_)                                        \
          ra[s_][m_ * 4 + ks_ * 2 + h_] = *(const f32x4*)(                    \
              abase + m_ * (16 * D_FEAT * 4) + (kt_) * 256 + ks_ * 128 + h_ * 16); \
  } while (0)

#define COMPUTE(s_, db_) do {                                                 \
    s16x8 fr[2][2];                                                           \
    _Pragma("unroll")                                                         \
    for (int m_ = 0; m_ < 2; ++m_)                                            \
      _Pragma("unroll")                                                       \
      for (int ks_ = 0; ks_ < 2; ++ks_) {                                     \
        union { u32x4 u; s16x8 s; } pk_;                                      \
        f32x4 f0_ = ra[s_][m_ * 4 + ks_ * 2];                                 \
        f32x4 f1_ = ra[s_][m_ * 4 + ks_ * 2 + 1];                             \
        pk_.u[0] = cvt_pk(f0_[0], f0_[1]); pk_.u[1] = cvt_pk(f0_[2], f0_[3]); \
        pk_.u[2] = cvt_pk(f1_[0], f1_[1]); pk_.u[3] = cvt_pk(f1_[2], f1_[3]); \
        fr[m_][ks_] = pk_.s;                                                  \
      }                                                                       \
    __builtin_amdgcn_s_setprio(1);                                            \
    _Pragma("unroll")                                                         \
    for (int ks_ = 0; ks_ < 2; ++ks_) {                                       \
      int sl_ = ks_ * 4 + lh;                                                 \
      _Pragma("unroll")                                                       \
      for (int nf_ = 0; nf_ < 4; ++nf_) {                                     \
        int nl_ = nf_ * 16 + l15;                                             \
        s16x8 b_ = *(const s16x8*)(Bme + (db_) * 8192 + nl_ * 128 +           \
                                   ((sl_ ^ (nl_ & 7)) << 4));                 \
        acc[0][nf_] = __builtin_amdgcn_mfma_f32_16x16x32_bf16(fr[0][ks_], b_, acc[0][nf_], 0, 0, 0); \
        acc[1][nf_] = __builtin_amdgcn_mfma_f32_16x16x32_bf16(fr[1][ks_], b_, acc[1][nf_], 0, 0, 0); \
      }                                                                       \
    }                                                                         \
    __builtin_amdgcn_s_setprio(0);                                            \
  } while (0)

  // ITER(kt): [vmcnt(8): retire A(kt)+B(kt), A(kt+1) stays in flight]
  // [issue B(kt+1), A(kt+2)] [cvt A(kt) + compute tile kt]. No barriers.
#define ITER(kt_, db_, dbn_, sc_, sn_) do {                                   \
    asm volatile("s_waitcnt vmcnt(8)" ::: "memory");                          \
    __builtin_amdgcn_sched_barrier(0);                                        \
    STAGEB((kt_) + 1, dbn_);                                                  \
    LOADA((kt_) + 2, sn_);                                                    \
    __builtin_amdgcn_sched_barrier(0);                                        \
    COMPUTE(sc_, db_);                                                        \
  } while (0)

  // ---- prologue: queue = [B0:8, A0:8, A1:8] = 24 --------------------------
  STAGEB(0, 0);
  LOADA(0, 0);
  LOADA(1, 1);

  // ---- main loop: kt = 0..17 (period lcm(2,3)=6), tails 18,19 -------------
  for (int t = 0; t < 3; ++t) {
    ITER(6 * t + 0, 0, 1, 0, 2);
    ITER(6 * t + 1, 1, 0, 1, 0);
    ITER(6 * t + 2, 0, 1, 2, 1);
    ITER(6 * t + 3, 1, 0, 0, 2);
    ITER(6 * t + 4, 0, 1, 1, 0);
    ITER(6 * t + 5, 1, 0, 2, 1);
  }
  // kt=18: queue [A18:8, B18:8, A19:8] -> vmcnt(8); stage B19 only
  asm volatile("s_waitcnt vmcnt(8)" ::: "memory");
  __builtin_amdgcn_sched_barrier(0);
  STAGEB(19, 1);
  __builtin_amdgcn_sched_barrier(0);
  COMPUTE(0, 0);                                   // tile 18 (slot 18%3=0, buf 0)
  // kt=19: queue [A19:8, B19:8] -> vmcnt(0)
  asm volatile("s_waitcnt vmcnt(0)" ::: "memory");
  __builtin_amdgcn_sched_barrier(0);
  COMPUTE(1, 1);                                   // tile 19 (slot 1, buf 1)

  __syncthreads();   // first and only block-wide sync: publish acc via LDS

  // ---- epilogue: logits -> LDS, column-major stride 33 ---------------------
  float* Ls = (float*)smem;            // Ls[col*33 + row], col<248 (32.7 KB)
#pragma unroll
  for (int m = 0; m < 2; ++m)
#pragma unroll
    for (int nf = 0; nf < 4; ++nf) {
      int col = wave * 64 + nf * 16 + l15;
      if (col < N_OUT) {
        int rbase = m * 16 + (lh << 2);
#pragma unroll
        for (int i = 0; i < 4; ++i) Ls[col * 33 + rbase + i] = acc[m][nf][i];
      }
    }
  __syncthreads();

  // 8 threads per row: part p owns root i=p entirely (u1, level-1, level-2).
  const int p = tid & 7;
  const int r = tid >> 3;              // 0..31
  float* orow = out + (size_t)(row0 + r) * N_OUT;

  float ui = Ls[p * 33 + r] + b_final[p];
  orow[p] = ui;

  // level-1: softmax over 6, then u2 = p1 * u1
  float lg[6];
  float mx = -1e30f;
#pragma unroll
  for (int c = 0; c < 6; ++c) {
    lg[c] = Ls[(8 + p * 6 + c) * 33 + r] + ui * wu1[p * 6 + c] + b1[p * 6 + c];
    mx = fmaxf(mx, lg[c]);
  }
  float s = 0.0f;
#pragma unroll
  for (int c = 0; c < 6; ++c) { lg[c] = __expf(lg[c] - mx); s += lg[c]; }
  float sc = ui / s;
  float u2v[6];
#pragma unroll
  for (int c = 0; c < 6; ++c) {
    u2v[c] = lg[c] * sc;
    orow[8 + p * 6 + c] = u2v[c];
  }

  // level-2: 6 groups of 4, u3 = p2 * u2
#pragma unroll
  for (int j = 0; j < 6; ++j) {
    int g = p * 6 + j;
    float ug = u2v[j];
    float l2[4];
    float m2 = -1e30f;
#pragma unroll
    for (int c = 0; c < 4; ++c) {
      l2[c] = Ls[(56 + g * 4 + c) * 33 + r] + ug * wu2[g * 4 + c] + b2[g * 4 + c];
      m2 = fmaxf(m2, l2[c]);
    }
    float s2 = 0.0f;
#pragma unroll
    for (int c = 0; c < 4; ++c) { l2[c] = __expf(l2[c] - m2); s2 += l2[c]; }
    float sc2 = ug / s2;
    f32x4 o;
#pragma unroll
    for (int c = 0; c < 4; ++c) o[c] = l2[c] * sc2;
    *(f32x4*)(orow + 56 + g * 4) = o;
  }
#undef STAGEB
#undef LOADA
#undef COMPUTE
#undef ITER
}

// ---------------------------------------------------------------------------
extern "C" void kernel_launch(void* const* d_in, const int* in_sizes, int n_in,
                              void* d_out, int out_size, void* d_ws, size_t ws_size,
                              hipStream_t stream) {
  const float* x   = (const float*)d_in[0];
  const float* Wf  = (const float*)d_in[1];
  const float* bf  = (const float*)d_in[2];
  const float* Wp1 = (const float*)d_in[3];
  const float* wu1 = (const float*)d_in[4];
  const float* b1  = (const float*)d_in[5];
  const float* Wp2 = (const float*)d_in[6];
  const float* wu2 = (const float*)d_in[7];
  const float* b2  = (const float*)d_in[8];
  float* out = (float*)d_out;
  unsigned short* Wb = (unsigned short*)d_ws;   // 655,360 B packed bf16 weights

  pack_w_kernel<<<160, 256, 0, stream>>>(Wf, Wp1, Wp2, Wb);
  tree_head_kernel<<<16384 / BM, 256, 0, stream>>>(x, Wb, bf, wu1, b1, wu2, b2, out);
}

// Round 10
// 37.359 us; speedup vs baseline: 1.6397x; 1.6397x over previous
//
#include <hip/hip_runtime.h>
#include <stdint.h>
#include <stddef.h>

// Problem constants
#define D_FEAT 1280
#define N_PAD  256
#define N_OUT  248
#define BM     64
#define BK     64
#define K_ITERS 20
#define W_TILE_BYTES (N_PAD * BK * 2)   // 32 KB bf16 weight tile

typedef float f32x4 __attribute__((ext_vector_type(4)));
typedef short s16x8 __attribute__((ext_vector_type(8)));
typedef unsigned int u32x4 __attribute__((ext_vector_type(4)));

// one v_cvt_pk_bf16_f32: packs 2 fp32 -> 2 bf16 (RTNE), lo=a, hi=b
__device__ __forceinline__ unsigned int cvt_pk(float a, float b) {
  unsigned int r;
  asm("v_cvt_pk_bf16_f32 %0, %1, %2" : "=v"(r) : "v"(a), "v"(b));
  return r;
}

__device__ __forceinline__ void gload16(const void* g, void* l) {
  __builtin_amdgcn_global_load_lds(
      (const __attribute__((address_space(1))) void*)g,
      (__attribute__((address_space(3))) void*)l, 16, 0, 0);
}

// ---------------------------------------------------------------------------
// Pack W_final (D,8), Wp1 (8,D,6), Wp2 (8,6,D,4) into one bf16 matrix laid out
// exactly as the main kernel's LDS B-tiles expect (XOR swizzle pre-baked so
// global_load_lds is a LINEAR copy and ds_read_b128 is conflict-free).
// Tile kt: [n=0..255][s_phys=0..7] 16B chunks; chunk(n,s_phys) holds
// W[n][kt*64 + 8*(s_phys ^ (n&7)) .. +7].  One thread = one 16B chunk.
// ---------------------------------------------------------------------------
__global__ __launch_bounds__(256) void pack_w_kernel(
    const float* __restrict__ Wf, const float* __restrict__ Wp1,
    const float* __restrict__ Wp2, unsigned short* __restrict__ out) {
  int chunk = blockIdx.x * 256 + threadIdx.x;    // 0 .. 40959
  int s_phys = chunk & 7;
  int n = (chunk >> 3) & 255;
  int kt = chunk >> 11;
  int s_log = s_phys ^ (n & 7);
  int d0 = kt * BK + s_log * 8;
  float v[8];
#pragma unroll
  for (int e = 0; e < 8; ++e) v[e] = 0.0f;
  if (n < 8) {
#pragma unroll
    for (int e = 0; e < 8; ++e) v[e] = Wf[(d0 + e) * 8 + n];
  } else if (n < 56) {
    int m = n - 8;
    const float* base = Wp1 + (size_t)(m / 6) * D_FEAT * 6 + (m % 6);
#pragma unroll
    for (int e = 0; e < 8; ++e) v[e] = base[(d0 + e) * 6];
  } else if (n < 248) {
    int m = n - 56;
    const float* base = Wp2 + ((size_t)(m / 24) * 6 + ((m % 24) >> 2)) * D_FEAT * 4 + (m & 3);
#pragma unroll
    for (int e = 0; e < 8; ++e) v[e] = base[(d0 + e) * 4];
  }
  union { u32x4 u; s16x8 s; } pk;
#pragma unroll
  for (int h = 0; h < 4; ++h) pk.u[h] = cvt_pk(v[2 * h], v[2 * h + 1]);
  *(s16x8*)(out + (size_t)chunk * 8) = pk.s;
}

// ---------------------------------------------------------------------------
// Fused GEMM (bf16 MFMA) + hierarchical softmax epilogue.
// 512 threads = 8 waves (2M x 4N), BM=64, grid 256. LDS = 80 KB
// (2x8KB bf16 A dbuf + 2x32KB B dbuf) -> TWO blocks/CU = 16 waves/CU (50%
// occupancy): two independent 8-wave barrier domains overlap each other's
// per-iteration bubbles (the untested cell of the R4/R6/R8 ladder).
//
// Protocol (R8-proven wait-then-barrier): entering ITER(kt) the per-wave
// VMEM queue is [A(kt+1):2, B(kt):4, A(kt+2):2]; vmcnt(2) retires OWN
// A(kt+1)+B(kt) BEFORE s_barrier (cooperative staging rule), barrier
// certifies all waves' quarters landed. Then WRITEA(A(kt+1)) into the other
// A buffer, issue B(kt+1)+A(kt+3), compute tile kt.
// A: 2-iter flight via 3 reg slots; cvt_pk once; ds_write LDS[row][slot^(row&7)].
// B: pre-swizzled bf16 via global_load_lds, 1 compute-phase of flight.
// ---------------------------------------------------------------------------
__global__ __launch_bounds__(512, 4) void tree_head_kernel(
    const float* __restrict__ x, const unsigned short* __restrict__ Wb,
    const float* __restrict__ b_final, const float* __restrict__ wu1,
    const float* __restrict__ b1, const float* __restrict__ wu2,
    const float* __restrict__ b2, float* __restrict__ out) {
  __shared__ __align__(16) char smem[81920];   // Ab0,Ab1 (8KB ea) + Bb0,Bb1 (32KB ea)
  char* Ab0 = smem;
  char* Ab1 = smem + 8192;
  char* Bb0 = smem + 16384;
  char* Bb1 = smem + 49152;

  const int tid  = threadIdx.x;
  const int lane = tid & 63;
  const int wave = tid >> 6;       // 0..7
  const int wm   = wave >> 2;      // 0..1 (M half)
  const int wn   = wave & 3;       // 0..3 (N quarter)
  const int l15  = lane & 15;
  const int lh   = lane >> 4;      // 0..3
  const int row0 = blockIdx.x * BM;

  f32x4 acc[2][4];
#pragma unroll
  for (int m = 0; m < 2; ++m)
#pragma unroll
    for (int n = 0; n < 4; ++n)
#pragma unroll
      for (int j = 0; j < 4; ++j) acc[m][n][j] = 0.0f;

  // A staging: thread t owns row=t>>3 (0..63), slot=t&7 (8 k's: 32B fp32)
  const int arow = tid >> 3;
  const int aslot = tid & 7;
  const char* aptr = (const char*)x + ((size_t)(row0 + arow) * D_FEAT + aslot * 8) * 4;
  const int awoff = arow * 128 + ((aslot ^ (arow & 7)) << 4);
  // B staging: 4 gload_lds per thread, linear copy of pre-swizzled tile
  const char* bsrc = (const char*)Wb + wave * 1024 + lane * 16;
  const int bdst = wave * 1024;

  f32x4 ra[3][2];   // A fp32 prefetch regs, 3-slot rotation (static indices)

#define STAGEB(kt_, dB_) do {                                                 \
    _Pragma("unroll")                                                         \
    for (int j_ = 0; j_ < 4; ++j_)                                            \
      gload16(bsrc + (size_t)(kt_) * W_TILE_BYTES + j_ * 8192,                \
              (dB_) + bdst + j_ * 8192);                                      \
  } while (0)

#define LOADA(kt_, ri_) do {                                                  \
    ra[ri_][0] = *(const f32x4*)(aptr + (kt_) * 256);                         \
    ra[ri_][1] = *(const f32x4*)(aptr + (kt_) * 256 + 16);                    \
  } while (0)

#define WRITEA(ri_, dA_) do {                                                 \
    union { u32x4 u; s16x8 s; } pk_;                                          \
    pk_.u[0] = cvt_pk(ra[ri_][0][0], ra[ri_][0][1]);                          \
    pk_.u[1] = cvt_pk(ra[ri_][0][2], ra[ri_][0][3]);                          \
    pk_.u[2] = cvt_pk(ra[ri_][1][0], ra[ri_][1][1]);                          \
    pk_.u[3] = cvt_pk(ra[ri_][1][2], ra[ri_][1][3]);                          \
    *(s16x8*)((dA_) + awoff) = pk_.s;                                         \
  } while (0)

#define COMPUTE(cA_, cB_) do {                                                \
    s16x8 fr[2][2];                                                           \
    _Pragma("unroll")                                                         \
    for (int m_ = 0; m_ < 2; ++m_) {                                          \
      int rl_ = wm * 32 + m_ * 16 + l15;                                      \
      _Pragma("unroll")                                                       \
      for (int ks_ = 0; ks_ < 2; ++ks_) {                                     \
        int sl_ = ks_ * 4 + lh;                                               \
        fr[m_][ks_] = *(const s16x8*)((cA_) + rl_ * 128 +                     \
                                      ((sl_ ^ (rl_ & 7)) << 4));              \
      }                                                                       \
    }                                                                         \
    _Pragma("unroll")                                                         \
    for (int ks_ = 0; ks_ < 2; ++ks_) {                                       \
      int sl_ = ks_ * 4 + lh;                                                 \
      _Pragma("unroll")                                                       \
      for (int nf_ = 0; nf_ < 4; ++nf_) {                                     \
        int n_ = wn * 64 + nf_ * 16 + l15;                                    \
        s16x8 b_ = *(const s16x8*)((cB_) + n_ * 128 + ((sl_ ^ (n_ & 7)) << 4));\
        acc[0][nf_] = __builtin_amdgcn_mfma_f32_16x16x32_bf16(fr[0][ks_], b_, acc[0][nf_], 0, 0, 0); \
        acc[1][nf_] = __builtin_amdgcn_mfma_f32_16x16x32_bf16(fr[1][ks_], b_, acc[1][nf_], 0, 0, 0); \
      }                                                                       \
    }                                                                         \
  } while (0)

  // ITER(kt): [vmcnt(2) lgkmcnt(0): retire OWN A(kt+1)+B(kt) BEFORE barrier]
  // [s_barrier] [WRITEA A(kt+1) -> other A buf] [issue B(kt+1), A(kt+3)]
  // [compute tile kt]
#define ITER(cA_, cB_, wA_, sB_, skt_, lakt_, ls_, ws_) do {                  \
    asm volatile("s_waitcnt vmcnt(2) lgkmcnt(0)" ::: "memory");               \
    __builtin_amdgcn_sched_barrier(0);                                        \
    __builtin_amdgcn_s_barrier();                                             \
    __builtin_amdgcn_sched_barrier(0);                                        \
    WRITEA(ws_, wA_);                                                         \
    STAGEB(skt_, sB_);                                                        \
    LOADA(lakt_, ls_);                                                        \
    __builtin_amdgcn_sched_barrier(0);                                        \
    COMPUTE(cA_, cB_);                                                        \
  } while (0)

  // ---- prologue: queue = [A0:2, A1:2, B0:4, A2:2] = 10 --------------------
  LOADA(0, 0);
  LOADA(1, 1);
  STAGEB(0, Bb0);
  LOADA(2, 2);
  __builtin_amdgcn_sched_barrier(0);
  asm volatile("s_waitcnt vmcnt(8)" ::: "memory");   // retires A0
  __builtin_amdgcn_sched_barrier(0);
  WRITEA(0, Ab0);
  // entering kt=0: outstanding [A1:2, B0:4, A2:2] = 8

  // ---- main loop: kt = 0..11 (period 6), then 12..16 explicit -------------
  for (int t = 0; t < 2; ++t) {
    ITER(Ab0, Bb0, Ab1, Bb1, 6 * t + 1, 6 * t + 3, 0, 1);   // kt = 6t
    ITER(Ab1, Bb1, Ab0, Bb0, 6 * t + 2, 6 * t + 4, 1, 2);   // kt = 6t+1
    ITER(Ab0, Bb0, Ab1, Bb1, 6 * t + 3, 6 * t + 5, 2, 0);   // kt = 6t+2
    ITER(Ab1, Bb1, Ab0, Bb0, 6 * t + 4, 6 * t + 6, 0, 1);   // kt = 6t+3
    ITER(Ab0, Bb0, Ab1, Bb1, 6 * t + 5, 6 * t + 7, 1, 2);   // kt = 6t+4
    ITER(Ab1, Bb1, Ab0, Bb0, 6 * t + 6, 6 * t + 8, 2, 0);   // kt = 6t+5
  }
  ITER(Ab0, Bb0, Ab1, Bb1, 13, 15, 0, 1);                   // kt = 12
  ITER(Ab1, Bb1, Ab0, Bb0, 14, 16, 1, 2);                   // kt = 13
  ITER(Ab0, Bb0, Ab1, Bb1, 15, 17, 2, 0);                   // kt = 14
  ITER(Ab1, Bb1, Ab0, Bb0, 16, 18, 0, 1);                   // kt = 15
  ITER(Ab0, Bb0, Ab1, Bb1, 17, 19, 1, 2);                   // kt = 16
  // queue now: [A18:2, B17:4, A19:2] = 8

  // ---- tails ---------------------------------------------------------------
  // kt=17: vmcnt(2) retires A18+B17; write A18; stage B18; compute 17
  asm volatile("s_waitcnt vmcnt(2) lgkmcnt(0)" ::: "memory");
  __builtin_amdgcn_sched_barrier(0);
  __builtin_amdgcn_s_barrier();
  __builtin_amdgcn_sched_barrier(0);
  WRITEA(0, Ab0);                                    // A(18) -> Ab0
  STAGEB(18, Bb0);
  __builtin_amdgcn_sched_barrier(0);
  COMPUTE(Ab1, Bb1);                                 // tile 17
  // queue: [A19:2, B18:4] = 6

  // kt=18: vmcnt(0) retires A19+B18; write A19; stage B19; compute 18
  asm volatile("s_waitcnt vmcnt(0) lgkmcnt(0)" ::: "memory");
  __builtin_amdgcn_sched_barrier(0);
  __builtin_amdgcn_s_barrier();
  __builtin_amdgcn_sched_barrier(0);
  WRITEA(1, Ab1);                                    // A(19) -> Ab1
  STAGEB(19, Bb1);
  __builtin_amdgcn_sched_barrier(0);
  COMPUTE(Ab0, Bb0);                                 // tile 18
  // queue: [B19:4]

  // kt=19: vmcnt(0) retires B19; compute 19
  asm volatile("s_waitcnt vmcnt(0) lgkmcnt(0)" ::: "memory");
  __builtin_amdgcn_sched_barrier(0);
  __builtin_amdgcn_s_barrier();
  __builtin_amdgcn_sched_barrier(0);
  COMPUTE(Ab1, Bb1);                                 // tile 19

  __syncthreads();   // full drain before smem reuse as Ls

  // ---- epilogue: logits -> LDS, column-major stride 65 --------------------
  float* Ls = (float*)smem;            // Ls[col*65 + row], col<248 (64.5 KB)
#pragma unroll
  for (int m = 0; m < 2; ++m)
#pragma unroll
    for (int nf = 0; nf < 4; ++nf) {
      int col = wn * 64 + nf * 16 + l15;
      if (col < N_OUT) {
        int rbase = wm * 32 + m * 16 + (lh << 2);
#pragma unroll
        for (int i = 0; i < 4; ++i) Ls[col * 65 + rbase + i] = acc[m][nf][i];
      }
    }
  __syncthreads();

  // 8 threads per row: part p owns root i=p entirely (u1, level-1, level-2).
  const int p = tid & 7;
  const int r = tid >> 3;              // 0..63
  float* orow = out + (size_t)(row0 + r) * N_OUT;

  float ui = Ls[p * 65 + r] + b_final[p];
  orow[p] = ui;

  // level-1: softmax over 6, then u2 = p1 * u1
  float lg[6];
  float mx = -1e30f;
#pragma unroll
  for (int c = 0; c < 6; ++c) {
    lg[c] = Ls[(8 + p * 6 + c) * 65 + r] + ui * wu1[p * 6 + c] + b1[p * 6 + c];
    mx = fmaxf(mx, lg[c]);
  }
  float s = 0.0f;
#pragma unroll
  for (int c = 0; c < 6; ++c) { lg[c] = __expf(lg[c] - mx); s += lg[c]; }
  float sc = ui / s;
  float u2v[6];
#pragma unroll
  for (int c = 0; c < 6; ++c) {
    u2v[c] = lg[c] * sc;
    orow[8 + p * 6 + c] = u2v[c];
  }

  // level-2: 6 groups of 4, u3 = p2 * u2
#pragma unroll
  for (int j = 0; j < 6; ++j) {
    int g = p * 6 + j;
    float ug = u2v[j];
    float l2[4];
    float m2 = -1e30f;
#pragma unroll
    for (int c = 0; c < 4; ++c) {
      l2[c] = Ls[(56 + g * 4 + c) * 65 + r] + ug * wu2[g * 4 + c] + b2[g * 4 + c];
      m2 = fmaxf(m2, l2[c]);
    }
    float s2 = 0.0f;
#pragma unroll
    for (int c = 0; c < 4; ++c) { l2[c] = __expf(l2[c] - m2); s2 += l2[c]; }
    float sc2 = ug / s2;
    f32x4 o;
#pragma unroll
    for (int c = 0; c < 4; ++c) o[c] = l2[c] * sc2;
    *(f32x4*)(orow + 56 + g * 4) = o;
  }
#undef STAGEB
#undef LOADA
#undef WRITEA
#undef COMPUTE
#undef ITER
}

// ---------------------------------------------------------------------------
extern "C" void kernel_launch(void* const* d_in, const int* in_sizes, int n_in,
                              void* d_out, int out_size, void* d_ws, size_t ws_size,
                              hipStream_t stream) {
  const float* x   = (const float*)d_in[0];
  const float* Wf  = (const float*)d_in[1];
  const float* bf  = (const float*)d_in[2];
  const float* Wp1 = (const float*)d_in[3];
  const float* wu1 = (const float*)d_in[4];
  const float* b1  = (const float*)d_in[5];
  const float* Wp2 = (const float*)d_in[6];
  const float* wu2 = (const float*)d_in[7];
  const float* b2  = (const float*)d_in[8];
  float* out = (float*)d_out;
  unsigned short* Wb = (unsigned short*)d_ws;   // 655,360 B packed bf16 weights

  pack_w_kernel<<<160, 256, 0, stream>>>(Wf, Wp1, Wp2, Wb);
  tree_head_kernel<<<16384 / BM, 512, 0, stream>>>(x, Wb, bf, wu1, b1, wu2, b2, out);
}

// Round 12
// 35.154 us; speedup vs baseline: 1.7426x; 1.0627x over previous
//
#include <hip/hip_runtime.h>
#include <stdint.h>
#include <stddef.h>

// Problem constants
#define D_FEAT 1280
#define N_PAD  256
#define N_OUT  248
#define BM     64
#define K_ITERS 20

typedef float f32x4 __attribute__((ext_vector_type(4)));
typedef short s16x8 __attribute__((ext_vector_type(8)));
typedef unsigned int u32x4 __attribute__((ext_vector_type(4)));

// one v_cvt_pk_bf16_f32: packs 2 fp32 -> 2 bf16 (RTNE), lo=a, hi=b
__device__ __forceinline__ unsigned int cvt_pk(float a, float b) {
  unsigned int r;
  asm("v_cvt_pk_bf16_f32 %0, %1, %2" : "=v"(r) : "v"(a), "v"(b));
  return r;
}

// ---------------------------------------------------------------------------
// Pack W into FRAGMENT-DIRECT order: 16B chunk c = ((kt*2+ks)*16 + nf)*64 + lane
// holds W[n = nf*16 + (lane&15)][d = kt*64 + ks*32 + (lane>>4)*8 .. +7] as bf16.
// A wave's B-fragment load is then ONE coalesced global_load_dwordx4
// (wave-uniform base + lane*16) -> B never touches LDS in the main kernel.
// Column map: n<8 -> W_final[:,n]; 8..55 -> Wp1; 56..247 -> Wp2; 248..255 zero.
// ---------------------------------------------------------------------------
__global__ __launch_bounds__(256) void pack_w_kernel(
    const float* __restrict__ Wf, const float* __restrict__ Wp1,
    const float* __restrict__ Wp2, unsigned short* __restrict__ out) {
  int chunk = blockIdx.x * 256 + threadIdx.x;    // 0 .. 40959
  int lane = chunk & 63;
  int nf = (chunk >> 6) & 15;
  int ks = (chunk >> 10) & 1;
  int kt = chunk >> 11;
  int n = nf * 16 + (lane & 15);
  int d0 = kt * 64 + ks * 32 + (lane >> 4) * 8;
  float v[8];
#pragma unroll
  for (int e = 0; e < 8; ++e) v[e] = 0.0f;
  if (n < 8) {
#pragma unroll
    for (int e = 0; e < 8; ++e) v[e] = Wf[(d0 + e) * 8 + n];
  } else if (n < 56) {
    int m = n - 8;
    const float* base = Wp1 + (size_t)(m / 6) * D_FEAT * 6 + (m % 6);
#pragma unroll
    for (int e = 0; e < 8; ++e) v[e] = base[(d0 + e) * 6];
  } else if (n < 248) {
    int m = n - 56;
    const float* base = Wp2 + ((size_t)(m / 24) * 6 + ((m % 24) >> 2)) * D_FEAT * 4 + (m & 3);
#pragma unroll
    for (int e = 0; e < 8; ++e) v[e] = base[(d0 + e) * 4];
  }
  union { u32x4 u; s16x8 s; } pk;
#pragma unroll
  for (int h = 0; h < 4; ++h) pk.u[h] = cvt_pk(v[2 * h], v[2 * h + 1]);
  *(s16x8*)(out + (size_t)chunk * 8) = pk.s;
}

// ---------------------------------------------------------------------------
// Hybrid fused GEMM (bf16 MFMA) + hierarchical softmax epilogue.
// 512 threads = 8 waves, 1M x 8N: wave w = rows 0..63 x cols 32w..32w+31.
// B: register-direct coalesced global loads from fragment-packed Wb
//    (L2-resident, zero redundancy, NO LDS, NO barrier involvement).
// A: the only shared operand -> bf16 in LDS, staged 2 tiles (128 k) per
//    barrier: 16KB chunks, 32KB double-buffer; XOR slot swizzle.
// 10 barriers total, each guarding only the small A stage (lgkmcnt(0) only).
// All loads are PLAIN loads in straight-line fully-unrolled code: the
// compiler derives exact waitcnts (no manual vmcnt risk).
// ---------------------------------------------------------------------------
__global__ __launch_bounds__(512) void tree_head_kernel(
    const float* __restrict__ x, const unsigned short* __restrict__ Wb,
    const float* __restrict__ b_final, const float* __restrict__ wu1,
    const float* __restrict__ b1, const float* __restrict__ wu2,
    const float* __restrict__ b2, float* __restrict__ out) {
  __shared__ __align__(16) char smem[66560];   // 2x16KB A dbuf; 64.5KB Ls aliases
  char* L0 = smem;
  char* L1 = smem + 16384;

  const int tid  = threadIdx.x;
  const int lane = tid & 63;
  const int wave = tid >> 6;       // 0..7 = 32-col strip
  const int l15  = lane & 15;
  const int lh   = lane >> 4;      // 0..3
  const int row0 = blockIdx.x * BM;

  f32x4 acc[4][2];
#pragma unroll
  for (int m = 0; m < 4; ++m)
#pragma unroll
    for (int f = 0; f < 2; ++f)
#pragma unroll
      for (int j = 0; j < 4; ++j) acc[m][f][j] = 0.0f;

  // A staging: thread t owns row = t>>3 (0..63), k-group ak = t&7
  // (16 consecutive floats per super = slots 2ak, 2ak+1 of 16).
  const int arow = tid >> 3;
  const int ak   = tid & 7;
  const float* aptr = x + (size_t)(row0 + arow) * D_FEAT + ak * 16;
  const int s0 = 2 * ak, s1 = 2 * ak + 1;
  const int awoff0 = arow * 256 + (((s0 & 8) | ((s0 & 7) ^ (arow & 7))) << 4);
  const int awoff1 = arow * 256 + (((s1 & 8) | ((s1 & 7) ^ (arow & 7))) << 4);
  // B: fragment-direct; frag (kt,ks,f) at byte ((kt*2+ks)*16 + wave*2+f)*1024
  const char* wbase = (const char*)Wb + (wave * 2) * 1024 + lane * 16;

  f32x4 raE[4], raO[4];            // A fp32 prefetch, 2 supers in flight
  s16x8 bE[2][2][2], bO[2][2][2];  // B frags [tile-in-super][f][ks]

#define LOADA(S_, ra_) do {                                                   \
    _Pragma("unroll")                                                         \
    for (int q_ = 0; q_ < 4; ++q_)                                            \
      ra_[q_] = *(const f32x4*)(aptr + (S_) * 128 + q_ * 4);                  \
  } while (0)

#define WRITEA(ra_, L_) do {                                                  \
    union { u32x4 u; s16x8 s; } p0_, p1_;                                     \
    p0_.u[0] = cvt_pk(ra_[0][0], ra_[0][1]); p0_.u[1] = cvt_pk(ra_[0][2], ra_[0][3]); \
    p0_.u[2] = cvt_pk(ra_[1][0], ra_[1][1]); p0_.u[3] = cvt_pk(ra_[1][2], ra_[1][3]); \
    p1_.u[0] = cvt_pk(ra_[2][0], ra_[2][1]); p1_.u[1] = cvt_pk(ra_[2][2], ra_[2][3]); \
    p1_.u[2] = cvt_pk(ra_[3][0], ra_[3][1]); p1_.u[3] = cvt_pk(ra_[3][2], ra_[3][3]); \
    *(s16x8*)((L_) + awoff0) = p0_.s;                                         \
    *(s16x8*)((L_) + awoff1) = p1_.s;                                         \
  } while (0)

#define LOADB(kt_, b_) do {                                                   \
    _Pragma("unroll")                                                         \
    for (int f_ = 0; f_ < 2; ++f_)                                            \
      _Pragma("unroll")                                                       \
      for (int ks_ = 0; ks_ < 2; ++ks_)                                       \
        b_[f_][ks_] = *(const s16x8*)(wbase +                                 \
            ((size_t)((kt_) * 2 + ks_) * 16 + f_) * 1024);                    \
  } while (0)

  // COMPUTE tile u (0/1) of the super in LDS buffer L_, B frags b_[f][ks]
#define COMPUTE(u_, L_, b_) do {                                              \
    _Pragma("unroll")                                                         \
    for (int ks_ = 0; ks_ < 2; ++ks_) {                                       \
      _Pragma("unroll")                                                       \
      for (int m_ = 0; m_ < 4; ++m_) {                                        \
        int rl_ = m_ * 16 + l15;                                              \
        int sl_ = (u_) * 8 + ks_ * 4 + lh;                                    \
        int ph_ = (sl_ & 8) | ((sl_ & 7) ^ (rl_ & 7));                        \
        s16x8 fr_ = *(const s16x8*)((L_) + rl_ * 256 + (ph_ << 4));           \
        acc[m_][0] = __builtin_amdgcn_mfma_f32_16x16x32_bf16(fr_, b_[0][ks_], acc[m_][0], 0, 0, 0); \
        acc[m_][1] = __builtin_amdgcn_mfma_f32_16x16x32_bf16(fr_, b_[1][ks_], acc[m_][1], 0, 0, 0); \
      }                                                                       \
    }                                                                         \
  } while (0)

#define LGKMBAR() do {                                                        \
    asm volatile("s_waitcnt lgkmcnt(0)" ::: "memory");                        \
    __builtin_amdgcn_sched_barrier(0);                                        \
    __builtin_amdgcn_s_barrier();                                             \
    __builtin_amdgcn_sched_barrier(0);                                        \
  } while (0)

  // ---- prologue -----------------------------------------------------------
  LOADA(0, raE);
  LOADA(1, raO);
  LOADB(0, bE[0]);
  LOADB(1, bE[1]);
  WRITEA(raE, L0);                 // compiler waits raE only

  // ---- supers S=0..7 (tiles 0..15), period-2 unrolled ---------------------
#pragma unroll
  for (int t = 0; t < 4; ++t) {
    // S = 2t (even): read L0, publish A(2t+1)->L1
    LGKMBAR();
    WRITEA(raO, L1);
    LOADA(2 * t + 2, raE);
    LOADB(4 * t + 2, bO[0]);
    LOADB(4 * t + 3, bO[1]);
    COMPUTE(0, L0, bE[0]);
    COMPUTE(1, L0, bE[1]);
    // S = 2t+1 (odd): read L1, publish A(2t+2)->L0
    LGKMBAR();
    WRITEA(raE, L0);
    LOADA(2 * t + 3, raO);
    LOADB(4 * t + 4, bE[0]);
    LOADB(4 * t + 5, bE[1]);
    COMPUTE(0, L1, bO[0]);
    COMPUTE(1, L1, bO[1]);
  }
  // ---- S=8 (tiles 16,17): publish A(9)->L1, load last B pair --------------
  LGKMBAR();
  WRITEA(raO, L1);
  LOADB(18, bO[0]);
  LOADB(19, bO[1]);
  COMPUTE(0, L0, bE[0]);
  COMPUTE(1, L0, bE[1]);
  // ---- S=9 (tiles 18,19) --------------------------------------------------
  LGKMBAR();
  COMPUTE(0, L1, bO[0]);
  COMPUTE(1, L1, bO[1]);

  __syncthreads();   // full drain before smem reuse as Ls

  // ---- epilogue: logits -> LDS, column-major stride 65 --------------------
  float* Ls = (float*)smem;            // Ls[col*65 + row], col<248 (64.5 KB)
#pragma unroll
  for (int m = 0; m < 4; ++m)
#pragma unroll
    for (int f = 0; f < 2; ++f) {
      int col = wave * 32 + f * 16 + l15;
      if (col < N_OUT) {
        int rbase = m * 16 + (lh << 2);
#pragma unroll
        for (int i = 0; i < 4; ++i) Ls[col * 65 + rbase + i] = acc[m][f][i];
      }
    }
  __syncthreads();

  // 8 threads per row: part p owns root i=p entirely (u1, level-1, level-2).
  const int p = tid & 7;
  const int r = tid >> 3;              // 0..63
  float* orow = out + (size_t)(row0 + r) * N_OUT;

  float ui = Ls[p * 65 + r] + b_final[p];
  orow[p] = ui;

  // level-1: softmax over 6, then u2 = p1 * u1
  float lg[6];
  float mx = -1e30f;
#pragma unroll
  for (int c = 0; c < 6; ++c) {
    lg[c] = Ls[(8 + p * 6 + c) * 65 + r] + ui * wu1[p * 6 + c] + b1[p * 6 + c];
    mx = fmaxf(mx, lg[c]);
  }
  float s = 0.0f;
#pragma unroll
  for (int c = 0; c < 6; ++c) { lg[c] = __expf(lg[c] - mx); s += lg[c]; }
  float sc = ui / s;
  float u2v[6];
#pragma unroll
  for (int c = 0; c < 6; ++c) {
    u2v[c] = lg[c] * sc;
    orow[8 + p * 6 + c] = u2v[c];
  }

  // level-2: 6 groups of 4, u3 = p2 * u2
#pragma unroll
  for (int j = 0; j < 6; ++j) {
    int g = p * 6 + j;
    float ug = u2v[j];
    float l2[4];
    float m2 = -1e30f;
#pragma unroll
    for (int c = 0; c < 4; ++c) {
      l2[c] = Ls[(56 + g * 4 + c) * 65 + r] + ug * wu2[g * 4 + c] + b2[g * 4 + c];
      m2 = fmaxf(m2, l2[c]);
    }
    float s2 = 0.0f;
#pragma unroll
    for (int c = 0; c < 4; ++c) { l2[c] = __expf(l2[c] - m2); s2 += l2[c]; }
    float sc2 = ug / s2;
    f32x4 o;
#pragma unroll
    for (int c = 0; c < 4; ++c) o[c] = l2[c] * sc2;
    *(f32x4*)(orow + 56 + g * 4) = o;
  }
#undef LOADA
#undef WRITEA
#undef LOADB
#undef COMPUTE
#undef LGKMBAR
}

// ---------------------------------------------------------------------------
extern "C" void kernel_launch(void* const* d_in, const int* in_sizes, int n_in,
                              void* d_out, int out_size, void* d_ws, size_t ws_size,
                              hipStream_t stream) {
  const float* x   = (const float*)d_in[0];
  const float* Wf  = (const float*)d_in[1];
  const float* bf  = (const float*)d_in[2];
  const float* Wp1 = (const float*)d_in[3];
  const float* wu1 = (const float*)d_in[4];
  const float* b1  = (const float*)d_in[5];
  const float* Wp2 = (const float*)d_in[6];
  const float* wu2 = (const float*)d_in[7];
  const float* b2  = (const float*)d_in[8];
  float* out = (float*)d_out;
  unsigned short* Wb = (unsigned short*)d_ws;   // 655,360 B packed bf16 weights

  pack_w_kernel<<<160, 256, 0, stream>>>(Wf, Wp1, Wp2, Wb);
  tree_head_kernel<<<16384 / BM, 512, 0, stream>>>(x, Wb, bf, wu1, b1, wu2, b2, out);
}